// Round 1
// baseline (162.450 us; speedup 1.0000x reference)
//
#include <hip/hip_runtime.h>
#include <math.h>

#define NG 9
#define TILE 256

__device__ __forceinline__ float softplus_f(float x) {
    // stable: max(x,0) + log1p(exp(-|x|)); fast intrinsics are ~2 ulp, fine vs 2% tol
    float e = __expf(-fabsf(x));
    return fmaxf(x, 0.f) + __logf(1.f + e);
}

// Pass 1: classify each row, compact into toxic/non-toxic arrays, count per-group.
// cnts layout: [0]=nT, [1]=nN, [2..10]=cT[g] (toxic in group), [11..19]=cN[g]
__global__ __launch_bounds__(256) void k_prep(
    const float* __restrict__ logits, const float* __restrict__ ytox,
    const float* __restrict__ yid, int B,
    float* __restrict__ Tlog, int* __restrict__ Tmask,
    float* __restrict__ Nlog, int* __restrict__ Nmask,
    int* __restrict__ cnts) {
    int i = blockIdx.x * blockDim.x + threadIdx.x;
    if (i >= B) return;
    float l = logits[i];
    bool tox = ytox[i] >= 0.5f;
    int m = 0;
#pragma unroll
    for (int g = 0; g < NG; ++g)
        if (yid[i * NG + g] >= 0.5f) m |= (1 << g);
    if (tox) {
        int p = atomicAdd(&cnts[0], 1);
        Tlog[p] = l; Tmask[p] = m;
#pragma unroll
        for (int g = 0; g < NG; ++g)
            if ((m >> g) & 1) atomicAdd(&cnts[2 + g], 1);
    } else {
        int p = atomicAdd(&cnts[1], 1);
        Nlog[p] = l; Nmask[p] = m;
#pragma unroll
        for (int g = 0; g < NG; ++g)
            if ((m >> g) & 1) atomicAdd(&cnts[2 + NG + g], 1);
    }
}

// Pass 2: all (toxic i, non-toxic j) pairs. Thread owns one i; j tiles in LDS.
// num layout: num[t*NG+g], fp64, accumulated via atomics after block reduction.
__global__ __launch_bounds__(256) void k_pairs(
    const float* __restrict__ Tlog, const int* __restrict__ Tmask,
    const float* __restrict__ Nlog, const int* __restrict__ Nmask,
    const int* __restrict__ cnts, double* __restrict__ num) {
    __shared__ float sl[TILE];
    __shared__ int   smk[TILE];
    __shared__ float red[4][3 * NG];

    const int nT = cnts[0], nN = cnts[1];
    const int iBase = blockIdx.x * 256;
    if (iBase >= nT) return;                 // uniform exit
    const int nChunk = gridDim.y;
    const int per  = (nN + nChunk - 1) / nChunk;
    const int jBeg = blockIdx.y * per;
    const int jEnd = min(nN, jBeg + per);
    if (jBeg >= jEnd) return;                // uniform exit

    const int tid = threadIdx.x;
    const int i = iBase + tid;
    const bool active = i < nT;
    const float li = active ? Tlog[i] : 0.f;
    const int   mi = active ? Tmask[i] : 0;

    float Rall = 0.f;
    float Rg[NG];
#pragma unroll
    for (int g = 0; g < NG; ++g) Rg[g] = 0.f;

    for (int t = jBeg; t < jEnd; t += TILE) {
        const int n = min(TILE, jEnd - t);
        __syncthreads();
        if (tid < n) { sl[tid] = Nlog[t + tid]; smk[tid] = Nmask[t + tid]; }
        __syncthreads();
        for (int k = 0; k < n; ++k) {
            const float d = sl[k] - li;      // LDS broadcast read: conflict-free
            const int mj = smk[k];
            const float s = softplus_f(d);
            Rall += s;
#pragma unroll
            for (int g = 0; g < NG; ++g)
                Rg[g] += ((mj >> g) & 1) ? s : 0.f;
        }
    }

    if (!active) {
        Rall = 0.f;
#pragma unroll
        for (int g = 0; g < NG; ++g) Rg[g] = 0.f;
    }

    // fold per-thread accumulators into the 27 num partials
    float v[3 * NG];
#pragma unroll
    for (int g = 0; g < NG; ++g) {
        const bool a = (mi >> g) & 1;
        v[g]          = a ? Rg[g] : 0.f;            // t=0: i in group
        v[NG + g]     = a ? 0.f : Rg[g];            // t=1: i not in group
        v[2 * NG + g] = a ? (Rall - Rg[g]) : 0.f;   // t=2: i in group, j outside
    }
    const int lane = tid & 63;
    const int wave = tid >> 6;
#pragma unroll
    for (int r = 0; r < 3 * NG; ++r) {
        float x = v[r];
#pragma unroll
        for (int off = 32; off > 0; off >>= 1)
            x += __shfl_xor(x, off, 64);
        if (lane == 0) red[wave][r] = x;
    }
    __syncthreads();
    if (tid < 3 * NG) {
        float s = red[0][tid] + red[1][tid] + red[2][tid] + red[3][tid];
        atomicAdd(&num[tid], (double)s);
    }
}

// Pass 3: scalar epilogue in fp64.
__global__ void k_final(const double* __restrict__ num,
                        const int* __restrict__ cnts,
                        float* __restrict__ out) {
    if (threadIdx.x != 0 || blockIdx.x != 0) return;
    const long long nT = cnts[0], nN = cnts[1];
    double acc = 0.0; int ngv = 0;
    for (int g = 0; g < NG; ++g) {
        const long long cT = cnts[2 + g], cN = cnts[2 + NG + g];
        const long long c0 = cT * cN;
        const long long c1 = (nT - cT) * cN;
        const long long c2 = cT * (nN - cN);
        const double t0 = num[g]          / (double)(c0 > 0 ? c0 : 1);
        const double t1 = num[NG + g]     / (double)(c1 > 0 ? c1 : 1);
        const double t2 = num[2 * NG + g] / (double)(c2 > 0 ? c2 : 1);
        const int nv = (c0 > 0) + (c1 > 0) + (c2 > 0);
        const double gl = ((c0 > 0 ? t0 : 0.0) + (c1 > 0 ? t1 : 0.0) +
                           (c2 > 0 ? t2 : 0.0)) / (double)(nv > 0 ? nv : 1);
        if (nv > 0) { const double g2 = gl * gl; acc += g2 * g2; ++ngv; }
    }
    const double mean_p = acc / (double)(ngv > 0 ? ngv : 1);
    const double loss = pow(mean_p, 0.25);
    out[0] = (float)(ngv > 0 ? loss : 0.0);
}

extern "C" void kernel_launch(void* const* d_in, const int* in_sizes, int n_in,
                              void* d_out, int out_size, void* d_ws, size_t ws_size,
                              hipStream_t stream) {
    const float* logits = (const float*)d_in[0];
    const float* ytox   = (const float*)d_in[1];
    const float* yid    = (const float*)d_in[2];
    const int B = in_sizes[0];

    char* ws = (char*)d_ws;
    double* num  = (double*)ws;                    // 27 doubles (216 B), pad to 256
    int*    cnts = (int*)(ws + 256);               // 20 ints (80 B), pad to 512
    float*  Tlog = (float*)(ws + 512);
    int*    Tmask = (int*)(ws + 512 + 4 * (size_t)B);
    float*  Nlog = (float*)(ws + 512 + 8 * (size_t)B);
    int*    Nmask = (int*)(ws + 512 + 12 * (size_t)B);

    hipMemsetAsync(d_ws, 0, 512, stream);          // zero num + cnts (ws is poisoned)

    k_prep<<<dim3((B + 255) / 256), dim3(256), 0, stream>>>(
        logits, ytox, yid, B, Tlog, Tmask, Nlog, Nmask, cnts);

    dim3 grid((B + 255) / 256, 16);                // i-chunks x j-chunks (~512 blocks)
    k_pairs<<<grid, dim3(256), 0, stream>>>(Tlog, Tmask, Nlog, Nmask, cnts, num);

    k_final<<<dim3(1), dim3(64), 0, stream>>>(num, cnts, (float*)d_out);
}